// Round 13
// baseline (82.350 us; speedup 1.0000x reference)
//
#include <hip/hip_runtime.h>

// Chamfer distance, B=16, N=M=4096, D=3, fp32.
// v14: R12 (78.1us, chamfer ~30) audit: per-SIMD v_min work is only 13.7us
// => VALU duty ~46%, no longer VALU-bound. Remaining ~16us = un-overlapped
// ds->MFMA->min dependency time at just 4 waves/SIMD (512-block grid = 2
// blocks/CU, grid-limited). v14 recombines R12's lean prologue (direct
// stores, no atomics, single launch, 1x query pack) with R6/R10's 8
// waves/SIMD:
//  - 1024 blocks = 32 qtiles (128 q) x 16 batches x 2 dirs
//  - 4 target chunks of 1024 (LDS 32 KB) -> 4 blocks/CU x 8 waves
//    = 32 waves/CU = 8 waves/SIMD co-resident
//  - NQT=1: per tile 1 ds_read -> 1 MFMA -> 4 fminf; unroll-4 = 4
//    independent streams; TLP hides MFMA/ds latency
//  - staging 2 targets/thread/chunk via float2x3 (24B, coalesced-ish)
// Loop kept in the verified pure-fminf form (NO inline asm anywhere: R7-9
// asm-on-MFMA-dests corrupts; R11 asm-on-VALU deoptimizes ~+40%).
// Numerics = R11/R12 (passed, absmax 0.0078): K=11 bf16 hi/lo trunc splits,
// pack2 (v_perm) positionally matched on A and B so halfword order cancels.
// A kb0:{(X,Y),(Z,xl),(yl,zl),(X,Y)} kb1:{(Z,nt),(ntl,0),0,0};
// B kb0:{(MX,MY),(MZ,MX),(MY,MZ),(mxl,myl)} kb1:{(mzl,1),(1,0),0,0}, M=-2q.
// Lanes 32-63 mirror lanes 0-31's LDS reads (2-way broadcast, free per
// m136); their garbage A-frags multiply B's kb>=2 zero frags (finite*0=0).
// C/D map (m89): col=lane&15, row=(lane>>4)*4+reg; shfl_xor(16,32) min
// combines row-groups; kb==0 lanes store.

#define CB 16
#define CN 4096
#define CM 4096
#define WVS 8
#define QPW 16               // queries per wave (NQT=1)
#define QPB (WVS * QPW)      // 128 queries per block
#define TPC 1024             // targets per LDS chunk
#define NCH (CM / TPC)       // 4 chunks
#define NTT (TPC / 16)       // 64 tiles per chunk

typedef float f32x4 __attribute__((ext_vector_type(4)));
typedef float f32x2 __attribute__((ext_vector_type(2)));
typedef short bf16x8 __attribute__((ext_vector_type(8)));
typedef unsigned int u32;
typedef u32 u32x4 __attribute__((ext_vector_type(4)));

// pack2(a,b): halfwords = bf16_trunc(a), bf16_trunc(b); order is
// convention-dependent but positionally matched on A and B sides, so it
// cancels in the dot product. (R11/R12-verified.)
__device__ __forceinline__ u32 pack2(float a, float b) {
    return __builtin_amdgcn_perm(__float_as_uint(b), __float_as_uint(a),
                                 0x07060302u);
}
__device__ __forceinline__ float hi_f(float a) {     // bf16_trunc as f32
    return __uint_as_float(__float_as_uint(a) & 0xFFFF0000u);
}

// grid: (32 qtiles, 16 batches, 2 dirs) = 1024 blocks x 512 thr, 1 launch.
__global__ __launch_bounds__(512, 8) void chamfer_mfma(
    const float* __restrict__ x1, const float* __restrict__ x2,
    float* __restrict__ out)
{
    const int dir   = blockIdx.z;
    const int b     = blockIdx.y;
    const int qtile = blockIdx.x;        // 128-query tile

    const float* __restrict__ qraw = (dir ? x2 : x1) + (size_t)b * CN * 3;
    const float* __restrict__ traw = (dir ? x1 : x2) + (size_t)b * CM * 3;
    float* __restrict__ o = out + (dir ? ((size_t)CB * CN + (size_t)b * CM)
                                       : ((size_t)b * CN)) + qtile * QPB;

    // [tile][32]: entries 0-15 = word0 (K0-7) rows, 16-31 = word1 (K8-15).
    __shared__ u32x4 AI[NTT * 32];       // 32 KB

    const int tid  = threadIdx.x;
    const int lane = tid & 63;
    const int wave = __builtin_amdgcn_readfirstlane(tid >> 6);
    const int col  = lane & 15;          // C column = query index
    const int kb   = lane >> 4;
    const int lsel = lane & 31;          // lanes 32-63 mirror 0-31

    // ---- Query (once per block): wave covers [qtile*128 + wave*16, +16).
    bf16x8 bq;
    float nq;
    {
        const float* qp = qraw + (size_t)3 * (qtile * QPB + wave * QPW + col);
        float qx = qp[0], qy = qp[1], qz = qp[2];
        nq = fmaf(qx, qx, fmaf(qy, qy, qz * qz));
        float MX = -2.f * qx, MY = -2.f * qy, MZ = -2.f * qz;
        float mxl = MX - hi_f(MX);
        float myl = MY - hi_f(MY);
        float mzl = MZ - hi_f(MZ);
        u32x4 w;
        if (kb == 0)
            w = (u32x4){pack2(MX, MY), pack2(MZ, MX),
                        pack2(MY, MZ), pack2(mxl, myl)};
        else if (kb == 1)
            w = (u32x4){pack2(mzl, 1.0f), pack2(1.0f, 0.f), 0u, 0u};
        else
            w = (u32x4){0u, 0u, 0u, 0u};
        bq = __builtin_bit_cast(bf16x8, w);
    }

    float best0 = 1e30f, best1 = 1e30f;

    #pragma unroll 1
    for (int c = 0; c < NCH; ++c) {
        // ---- Stage chunk c: thread packs targets 2*tid, 2*tid+1 (24 B).
        {
            const f32x2* rv = (const f32x2*)(traw + (size_t)(c * TPC + 2 * tid) * 3);
            f32x2 r0 = rv[0], r1 = rv[1], r2 = rv[2];
            // r0=(t0x,t0y) r1=(t0z,t1x) r2=(t1y,t1z)
            const float tx[2] = {r0.x, r1.y};
            const float ty[2] = {r0.y, r2.x};
            const float tz[2] = {r1.x, r2.y};
            #pragma unroll
            for (int i = 0; i < 2; ++i) {
                float X = tx[i], Y = ty[i], Zc = tz[i];
                float xl = X - hi_f(X);
                float yl = Y - hi_f(Y);
                float zl = Zc - hi_f(Zc);
                float nt = fmaf(X, X, fmaf(Y, Y, Zc * Zc));
                float ntl = nt - hi_f(nt);
                const int r = 2 * tid + i;                 // chunk-local idx
                const int base = (r >> 4) * 32 + (r & 15);
                AI[base +  0] = (u32x4){pack2(X, Y), pack2(Zc, xl),
                                        pack2(yl, zl), pack2(X, Y)};
                AI[base + 16] = (u32x4){pack2(Zc, nt), pack2(ntl, 0.f),
                                        0u, 0u};
            }
        }
        __syncthreads();

        // ---- Sweep 64 tiles: 1 ds_read_b128 + 1 MFMA + 4 v_min per tile;
        // unroll-4 = 4 independent dep streams; 8 waves/SIMD hide latency.
        #pragma unroll 1
        for (int t = 0; t < NTT; t += 4) {
            #pragma unroll
            for (int u = 0; u < 4; ++u) {
                bf16x8 af = __builtin_bit_cast(bf16x8, AI[(t + u) * 32 + lsel]);
                f32x4 acc = __builtin_amdgcn_mfma_f32_16x16x32_bf16(
                    af, bq, (f32x4){0.f, 0.f, 0.f, 0.f}, 0, 0, 0);
                best0 = fminf(fminf(best0, acc.x), acc.y);
                best1 = fminf(fminf(best1, acc.z), acc.w);
            }
        }
        __syncthreads();   // before next chunk overwrites LDS
    }

    // ---- Combine row-groups, add |q|^2, clamp, direct store.
    float v = fminf(best0, best1);
    v = fminf(v, __shfl_xor(v, 16));
    v = fminf(v, __shfl_xor(v, 32));
    if (kb == 0)
        o[wave * QPW + col] = fmaxf(v + nq, 0.f);
}

extern "C" void kernel_launch(void* const* d_in, const int* in_sizes, int n_in,
                              void* d_out, int out_size, void* d_ws, size_t ws_size,
                              hipStream_t stream) {
    const float* x1 = (const float*)d_in[0];   // [B,N,3]
    const float* x2 = (const float*)d_in[1];   // [B,M,3]
    float* out = (float*)d_out;

    chamfer_mfma<<<dim3(32, CB, 2), 512, 0, stream>>>(x1, x2, out);
}

// Round 14
// 78.572 us; speedup vs baseline: 1.0481x; 1.0481x over previous
//
#include <hip/hip_runtime.h>

// Chamfer distance, B=16, N=M=4096, D=3, fp32.
// v15: R13 (NQT=1, 8 waves/SIMD) regressed 78->82: doubling ds_read count
// to 8192/CU put the LDS pipe (~12cyc/b128, m134) at 20-40us -- the real
// critical resource. Three-pipe ledger per CU: matrix 8192 MFMA x 4.85cyc
// = 16.6us (irreducible for 16x16x32), VALU mins 13.7us, LDS ~ reads x
// 6-12cyc. => raise MFMA:ds_read to 4:1 (NQT=4): LDS drops to ~5-10us,
// matrix becomes the sole critical pipe.
//  - 512 blocks = 8 qtiles (512 q) x 2 target-halves x 16 batches x 2 dirs
//  - block stages its 2048-target half (64KB LDS, 2 blocks/CU, 4 waves/SIMD
//    = R12's proven TLP point); 128 tiles x (1 ds_read + 4 MFMA + 16 v_min)
//  - target-halves merged via monotone-uint atomicMin into +inf-prefilled
//    out (R1-R11-verified path; all values >= 0)
// Loop is the verified pure-fminf form -- NO inline asm anywhere (R7-9:
// asm reading MFMA dests corrupts; R11: asm on VALU values deoptimizes).
// Numerics = R11/R12/R13 (absmax 0.0078): K=11 bf16 hi/lo trunc splits,
// pack2 (v_perm) positionally matched on A and B so halfword order cancels.
// A kb0:{(X,Y),(Z,xl),(yl,zl),(X,Y)} kb1:{(Z,nt),(ntl,0),0,0};
// B kb0:{(MX,MY),(MZ,MX),(MY,MZ),(mxl,myl)} kb1:{(mzl,1),(1,0),0,0}, M=-2q.
// Lanes 32-63 mirror lanes 0-31's LDS reads (same-addr broadcast); their
// garbage A-frags multiply B's kb>=2 zero frags (finite*0=0).
// C/D map (m89): col=lane&15, row=(lane>>4)*4+reg; shfl_xor(16,32) min
// combines row-groups; kb==0 lanes merge via atomicMin.

#define CB 16
#define CN 4096
#define CM 4096
#define WVS 8
#define NQT 4                // query tiles (of 16) per wave
#define QPW (NQT * 16)       // 64 queries per wave
#define QPB (WVS * QPW)      // 512 queries per block
#define TPH 2048             // targets per block (half the cloud)
#define NTT (TPH / 16)       // 128 tiles

typedef float f32x4 __attribute__((ext_vector_type(4)));
typedef short bf16x8 __attribute__((ext_vector_type(8)));
typedef unsigned int u32;
typedef u32 u32x4 __attribute__((ext_vector_type(4)));
typedef float v4f __attribute__((ext_vector_type(4)));

// pack2(a,b): halfwords = bf16_trunc(a), bf16_trunc(b); order is
// convention-dependent but positionally matched on A and B sides, so it
// cancels in the dot product. (R11-R13-verified.)
__device__ __forceinline__ u32 pack2(float a, float b) {
    return __builtin_amdgcn_perm(__float_as_uint(b), __float_as_uint(a),
                                 0x07060302u);
}
__device__ __forceinline__ float hi_f(float a) {     // bf16_trunc as f32
    return __uint_as_float(__float_as_uint(a) & 0xFFFF0000u);
}

__global__ void init_out(unsigned* __restrict__ out)
{
    out[blockIdx.x * 512 + threadIdx.x] = 0x7F800000u;  // +inf bits
}

// grid: (8 qtiles x 2 thalves, 16 batches, 2 dirs) = 512 blocks x 512 thr.
__global__ __launch_bounds__(512, 4) void chamfer_mfma(
    const float* __restrict__ x1, const float* __restrict__ x2,
    unsigned* __restrict__ out)
{
    const int dir   = blockIdx.z;
    const int b     = blockIdx.y;
    const int qtile = blockIdx.x & 7;    // 512-query tile
    const int thalf = blockIdx.x >> 3;   // 2048-target half

    const float* __restrict__ qraw = (dir ? x2 : x1) + (size_t)b * CN * 3;
    const float* __restrict__ traw = (dir ? x1 : x2) + (size_t)b * CM * 3
                                   + (size_t)thalf * TPH * 3;
    unsigned* __restrict__ o = out + (dir ? ((size_t)CB * CN + (size_t)b * CM)
                                          : ((size_t)b * CN)) + qtile * QPB;

    // [tile][32]: entries 0-15 = word0 (K0-7) rows, 16-31 = word1 (K8-15).
    __shared__ u32x4 AI[NTT * 32];       // 64 KB exactly

    const int tid  = threadIdx.x;
    const int lane = tid & 63;
    const int wave = __builtin_amdgcn_readfirstlane(tid >> 6);
    const int col  = lane & 15;          // C column = query index
    const int kb   = lane >> 4;
    const int lsel = lane & 31;          // lanes 32-63 mirror 0-31

    // ---- Stage 2048 targets: thread packs [4*tid, 4*tid+4) via 3 x 16B.
    {
        const v4f* rv = (const v4f*)(traw + (size_t)12 * tid);
        v4f r0 = rv[0], r1 = rv[1], r2 = rv[2];
        // r0=(t0x,t0y,t0z,t1x) r1=(t1y,t1z,t2x,t2y) r2=(t2z,t3x,t3y,t3z)
        const float tx[4] = {r0.x, r0.w, r1.z, r2.y};
        const float ty[4] = {r0.y, r1.x, r1.w, r2.z};
        const float tz[4] = {r0.z, r1.y, r2.x, r2.w};
        #pragma unroll
        for (int i = 0; i < 4; ++i) {
            float X = tx[i], Y = ty[i], Zc = tz[i];
            float xl = X - hi_f(X);
            float yl = Y - hi_f(Y);
            float zl = Zc - hi_f(Zc);
            float nt = fmaf(X, X, fmaf(Y, Y, Zc * Zc));
            float ntl = nt - hi_f(nt);
            const int r = 4 * tid + i;                 // local target idx
            const int base = (r >> 4) * 32 + (r & 15);
            AI[base +  0] = (u32x4){pack2(X, Y), pack2(Zc, xl),
                                    pack2(yl, zl), pack2(X, Y)};
            AI[base + 16] = (u32x4){pack2(Zc, nt), pack2(ntl, 0.f), 0u, 0u};
        }
    }

    // ---- Queries: wave covers [qtile*512 + wave*64, +64); lane's col.
    bf16x8 bq[NQT];
    float nq[NQT];
    #pragma unroll
    for (int qt = 0; qt < NQT; ++qt) {
        const float* qp = qraw
            + (size_t)3 * (qtile * QPB + wave * QPW + qt * 16 + col);
        float qx = qp[0], qy = qp[1], qz = qp[2];
        nq[qt] = fmaf(qx, qx, fmaf(qy, qy, qz * qz));
        float MX = -2.f * qx, MY = -2.f * qy, MZ = -2.f * qz;
        float mxl = MX - hi_f(MX);
        float myl = MY - hi_f(MY);
        float mzl = MZ - hi_f(MZ);
        u32x4 w;
        if (kb == 0)
            w = (u32x4){pack2(MX, MY), pack2(MZ, MX),
                        pack2(MY, MZ), pack2(mxl, myl)};
        else if (kb == 1)
            w = (u32x4){pack2(mzl, 1.0f), pack2(1.0f, 0.f), 0u, 0u};
        else
            w = (u32x4){0u, 0u, 0u, 0u};
        bq[qt] = __builtin_bit_cast(bf16x8, w);
    }

    float best0[NQT], best1[NQT];
    #pragma unroll
    for (int qt = 0; qt < NQT; ++qt) { best0[qt] = 1e30f; best1[qt] = 1e30f; }

    __syncthreads();

    // ---- Sweep 128 tiles: per tile 1 ds_read_b128 (512B, same-addr
    // broadcast for mirrored half) feeds 4 MFMA + 16 v_min. Unroll 2.
    #pragma unroll 1
    for (int t = 0; t < NTT; t += 2) {
        #pragma unroll
        for (int u = 0; u < 2; ++u) {
            bf16x8 af = __builtin_bit_cast(bf16x8, AI[(t + u) * 32 + lsel]);
            #pragma unroll
            for (int qt = 0; qt < NQT; ++qt) {
                f32x4 acc = __builtin_amdgcn_mfma_f32_16x16x32_bf16(
                    af, bq[qt], (f32x4){0.f, 0.f, 0.f, 0.f}, 0, 0, 0);
                best0[qt] = fminf(fminf(best0[qt], acc.x), acc.y);
                best1[qt] = fminf(fminf(best1[qt], acc.z), acc.w);
            }
        }
    }

    // ---- Combine row-groups, add |q|^2, clamp, atomic-merge the 2 halves.
    #pragma unroll
    for (int qt = 0; qt < NQT; ++qt) {
        float v = fminf(best0[qt], best1[qt]);
        v = fminf(v, __shfl_xor(v, 16));
        v = fminf(v, __shfl_xor(v, 32));
        if (kb == 0) {
            float val = fmaxf(v + nq[qt], 0.f);
            atomicMin(o + wave * QPW + qt * 16 + col, __float_as_uint(val));
        }
    }
}

extern "C" void kernel_launch(void* const* d_in, const int* in_sizes, int n_in,
                              void* d_out, int out_size, void* d_ws, size_t ws_size,
                              hipStream_t stream) {
    const float* x1 = (const float*)d_in[0];   // [B,N,3]
    const float* x2 = (const float*)d_in[1];   // [B,M,3]
    unsigned* out = (unsigned*)d_out;

    init_out<<<dim3(2 * CB * CN / 512), 512, 0, stream>>>(out);
    chamfer_mfma<<<dim3(16, CB, 2), 512, 0, stream>>>(x1, x2, out);
}

// Round 15
// 68.585 us; speedup vs baseline: 1.2007x; 1.1456x over previous
//
#include <hip/hip_runtime.h>

// Chamfer distance, B=16, N=M=4096, D=3, fp32.
// v16: R12-R14 + R10 all fit ONE model: per-SIMD, MFMA occupancy and VALU
// time ADD (R12: 2048 MFMA x 19.4cyc + 8192 v_min x 4 = 30.2us, obs ~30).
// So shrink the budgets: 32x32 MFMA = 1024 pairs per 8.07 cyc/CU (m119) vs
// 16x16x32's 256 per 4.85 -- 2.4x cheaper. R5 proved the gfx950-new
// 32x32x16 has asymmetric A/B k-maps; this uses the LEGACY
// v_mfma_f32_32x32x8_bf16 (ISA sec10: A=2,B=2,C=16 regs) whose documented
// CDNA layout is symmetric: row/col = lane%32, k = 4*(lane>>5)+i.
// K=8 packing (drops q-side low correction; B m-terms RNE-rounded to
// halve that error; est absmax 0.02-0.05 vs 0.12 threshold):
//   A = {Xh,Yh,Zh,xl | yl,zl,nt,ntl}   (xl=X-trunc(X) etc, nt=|t|^2 fp32,
//   B = {mx,my,mz,mx | my,mz, 1, 1}     ntl=nt-trunc(nt); m=RNE(-2q))
// products: X*mx+Y*my+Z*mz + xl*mx+yl*my+zl*mz + nt+ntl = |t|^2-2t.q.
// Every A and B word built via pack2 (position-matched; halfword order
// cancels -- R11/R12-verified construct). 16B/target => ALL 4096 targets in
// one 64KB LDS stage: single pass, direct stores, no atomics, one launch.
// Min tree is fusion-friendly fminf triples (exact reordering; if clang
// fuses to v_min3 the VALU budget halves; if not, identical to R12's form).
// NO inline asm anywhere (R7-9 corrupts, R11 deoptimizes).
// C/D map (m74/m101-verified): col=lane&31, row=(reg&3)+8*(reg>>2)+
// 4*(lane>>5) -> min over 16 regs + shfl_xor(32) covers all 32 rows.
// grid: (16 qtiles, 16 batches, 2 dirs) = 512 blocks x 512 thr (2/CU).

#define CB 16
#define CN 4096
#define CM 4096
#define WVS 8
#define QPW 32               // queries per wave (one 32-col tile)
#define QPB (WVS * QPW)      // 256 queries per block
#define NTT (CM / 32)        // 128 target tiles (whole cloud in LDS)

typedef float f32x16 __attribute__((ext_vector_type(16)));
typedef short bf16x4 __attribute__((ext_vector_type(4)));
typedef unsigned int u32;
typedef u32 u32x2 __attribute__((ext_vector_type(2)));

// pack2(a,b): halfwords = bf16_trunc(a), bf16_trunc(b); order is
// convention-dependent but positionally matched on A and B sides, so it
// cancels in the dot product. (R11-R14-verified.)
__device__ __forceinline__ u32 pack2(float a, float b) {
    return __builtin_amdgcn_perm(__float_as_uint(b), __float_as_uint(a),
                                 0x07060302u);
}
__device__ __forceinline__ float hi_f(float a) {     // bf16_trunc as f32
    return __uint_as_float(__float_as_uint(a) & 0xFFFF0000u);
}
__device__ __forceinline__ float rne_bf(float f) {   // RNE-to-bf16 as f32
    u32 u = __float_as_uint(f);
    u32 r = (u + 0x7FFFu + ((u >> 16) & 1u)) & 0xFFFF0000u;
    return __uint_as_float(r);
}

// grid: (16 qtiles, 16 batches, 2 dirs) = 512 blocks x 512 thr, 1 launch.
__global__ __launch_bounds__(512, 4) void chamfer_mfma(
    const float* __restrict__ x1, const float* __restrict__ x2,
    float* __restrict__ out)
{
    const int dir   = blockIdx.z;
    const int b     = blockIdx.y;
    const int qtile = blockIdx.x;        // 256-query tile

    const float* __restrict__ qraw = (dir ? x2 : x1) + (size_t)b * CN * 3;
    const float* __restrict__ traw = (dir ? x1 : x2) + (size_t)b * CM * 3;
    float* __restrict__ o = out + (dir ? ((size_t)CB * CN + (size_t)b * CM)
                                       : ((size_t)b * CN)) + qtile * QPB;

    // [tile][64]: entries 0-31 = rows' k0-3 words, 32-63 = rows' k4-7. 64 KB.
    __shared__ u32x2 AI[NTT * 64];

    const int tid  = threadIdx.x;
    const int lane = tid & 63;
    const int wave = __builtin_amdgcn_readfirstlane(tid >> 6);
    const int col  = lane & 31;
    const int h    = lane >> 5;

    // ---- Stage all 4096 targets: thread packs targets {tid + 512j}.
    // Per j: writes are two contiguous 256B runs -> conflict-free; global
    // reads coalesced (consecutive threads, consecutive 12B).
    #pragma unroll
    for (int j = 0; j < 8; ++j) {
        const int r = 512 * j + tid;
        const float* p = traw + 3 * r;
        float X = p[0], Y = p[1], Zc = p[2];
        float xl = X  - hi_f(X);
        float yl = Y  - hi_f(Y);
        float zl = Zc - hi_f(Zc);
        float nt  = fmaf(X, X, fmaf(Y, Y, Zc * Zc));
        float ntl = nt - hi_f(nt);
        const int e = (r >> 5) * 64 + (r & 31);
        AI[e]      = (u32x2){pack2(X, Y),   pack2(Zc, xl)};   // k0..k3
        AI[e + 32] = (u32x2){pack2(yl, zl), pack2(nt, ntl)};  // k4..k7
    }

    // ---- Query: wave covers [qtile*256 + wave*32, +32); lane's col.
    // B m-terms RNE-rounded (halves the uncompensated q-side error), then
    // pack2 so the halfword convention matches A exactly.
    float nq;
    bf16x4 bq;
    {
        const float* qp = qraw + (size_t)3 * (qtile * QPB + wave * QPW + col);
        float qx = qp[0], qy = qp[1], qz = qp[2];
        nq = fmaf(qx, qx, fmaf(qy, qy, qz * qz));
        float mx = rne_bf(-2.f * qx);
        float my = rne_bf(-2.f * qy);
        float mz = rne_bf(-2.f * qz);
        u32x2 w;
        if (h == 0)
            w = (u32x2){pack2(mx, my), pack2(mz, mx)};        // k0..k3
        else
            w = (u32x2){pack2(my, mz), pack2(1.0f, 1.0f)};    // k4..k7
        bq = __builtin_bit_cast(bf16x4, w);
    }

    float best = 1e30f;
    __syncthreads();

    // ---- Sweep 128 tiles: 1 ds_read_b64 + 1 MFMA + fusion-friendly min
    // tree (16 fminf, or 8 v_min3 if clang fuses). Unroll 4.
    #pragma unroll 1
    for (int t = 0; t < NTT; t += 4) {
        #pragma unroll
        for (int u = 0; u < 4; ++u) {
            bf16x4 af = __builtin_bit_cast(bf16x4, AI[(t + u) * 64 + lane]);
            f32x16 acc = __builtin_amdgcn_mfma_f32_32x32x8bf16_1k(
                af, bq, (f32x16)(0.f), 0, 0, 0);
            float t0 = fminf(fminf(acc[0],  acc[1]),  acc[2]);
            float t1 = fminf(fminf(acc[3],  acc[4]),  acc[5]);
            float t2 = fminf(fminf(acc[6],  acc[7]),  acc[8]);
            float t3 = fminf(fminf(acc[9],  acc[10]), acc[11]);
            float t4 = fminf(fminf(acc[12], acc[13]), acc[14]);
            float u0 = fminf(fminf(t0, t1), t2);
            float u1 = fminf(fminf(t3, t4), acc[15]);
            best = fminf(fminf(best, u0), u1);
        }
    }

    // ---- Combine the two half-row groups, add |q|^2, clamp, direct store.
    float v = fminf(best, __shfl_xor(best, 32));
    if (lane < 32)
        o[wave * QPW + col] = fmaxf(v + nq, 0.f);
}

extern "C" void kernel_launch(void* const* d_in, const int* in_sizes, int n_in,
                              void* d_out, int out_size, void* d_ws, size_t ws_size,
                              hipStream_t stream) {
    const float* x1 = (const float*)d_in[0];   // [B,N,3]
    const float* x2 = (const float*)d_in[1];   // [B,M,3]
    float* out = (float*)d_out;

    chamfer_mfma<<<dim3(16, CB, 2), 512, 0, stream>>>(x1, x2, out);
}